// Round 16
// baseline (81.976 us; speedup 1.0000x reference)
//
#include <hip/hip_runtime.h>
#include <hip/hip_bf16.h>

#define NB 8
#define SS 2048
#define DD 256
#define SCALE_INV 0.0625f

typedef __attribute__((ext_vector_type(8))) short bf16x8;
typedef __attribute__((ext_vector_type(4))) float f32x4;

#define MFMA __builtin_amdgcn_mfma_f32_16x16x32_bf16

// LDS: cs dbuf 64K, Ps dbuf 2x4608, part 512, invs 128  -> 75392 B (2 blocks/CU)
#define LB0   0
#define LB1   32768
#define LPS0  65536
#define LPS1  70144
#define LPART 74752
#define LINV  75264
#define LSMEM 75392

static __device__ __forceinline__ unsigned short f2bf(float f) {
  unsigned int u = __builtin_bit_cast(unsigned int, f);
  u += 0x7FFFu + ((u >> 16) & 1u);
  return (unsigned short)(u >> 16);
}
static __device__ __forceinline__ float bf2f(unsigned short s) {
  unsigned int u = ((unsigned int)s) << 16;
  return __builtin_bit_cast(float, u);
}

static __device__ __forceinline__ void gll16(const void* g, void* l) {
  __builtin_amdgcn_global_load_lds(
      (const __attribute__((address_space(1))) unsigned int*)g,
      (__attribute__((address_space(3))) unsigned int*)l, 16, 0, 0);
}

static __device__ __forceinline__ int load_len(const int* lp, int b) {
  bool is64 = ((lp[1] | lp[3] | lp[5] | lp[7]) == 0);
  return is64 ? lp[2 * b] : lp[b];
}

// ---------------- ctx f32 -> bf16 + transposed bf16 (proven) + dead-row skip ----------------
__global__ __launch_bounds__(256)
void preconv(const float* __restrict__ ctx,
             const int* __restrict__ lenp,
             unsigned short* __restrict__ cbf,   // [b][s][d]
             unsigned short* __restrict__ cT)    // [b][d][s]
{
  __shared__ unsigned short T[64][68];
  const int tid = threadIdx.x;
  const int s0 = blockIdx.x * 64, d0 = blockIdx.y * 64, b = blockIdx.z;

  // rows >= len[b] are never consumed by attn (sval-masked) -> skip conversion
  if (s0 >= load_len(lenp, b)) return;

  const int r = tid >> 4, c4 = tid & 15;

  #pragma unroll
  for (int i = 0; i < 4; ++i) {
    int row = i * 16 + r;
    size_t gi = ((size_t)(b * SS + s0 + row)) * DD + d0 + c4 * 4;
    float4 v = *(const float4*)(ctx + gi);
    ushort4 o;
    o.x = f2bf(v.x); o.y = f2bf(v.y); o.z = f2bf(v.z); o.w = f2bf(v.w);
    *(ushort4*)(cbf + gi) = o;
    T[c4 * 4 + 0][row] = o.x;
    T[c4 * 4 + 1][row] = o.y;
    T[c4 * 4 + 2][row] = o.z;
    T[c4 * 4 + 3][row] = o.w;
  }
  __syncthreads();
  const int rr = tid >> 2, cc = tid & 3;
  #pragma unroll
  for (int j = 0; j < 4; ++j) {
    size_t go = ((size_t)(b * DD + d0 + rr)) * SS + s0 + cc * 16 + j * 4;
    *(ushort4*)(cT + go) = *(const ushort4*)&T[rr][cc * 16 + j * 4];
  }
}

// ---------------- fused attention v16: v13 + adjacent pairing ----------------
__global__ __launch_bounds__(256, 2)
void attn_v16(const unsigned short* __restrict__ cbf,
              const unsigned short* __restrict__ cT,
              const float* __restrict__ qry,
              const int* __restrict__ lenp,
              float* __restrict__ att,
              float* __restrict__ sc)
{
  __shared__ __align__(16) unsigned char smem[LSMEM];

  const int tid = threadIdx.x;
  const int wv = tid >> 6;
  const int lane = tid & 63;
  const int l15 = lane & 15;
  const int l4 = lane >> 4;
  const int sl = wv * 16 + l15;

  // ---- length-sorted mapping; ADJACENT pairing: CU c hosts ranks (2c, 2c+1) ----
  int lens_[8];
  #pragma unroll
  for (int i = 0; i < 8; ++i) lens_[i] = load_len(lenp, i);
  int ord[8] = {0, 1, 2, 3, 4, 5, 6, 7};
  for (int i = 1; i < 8; ++i) {
    int key = ord[i], kl = lens_[key], j = i - 1;
    while (j >= 0 && lens_[ord[j]] < kl) { ord[j + 1] = ord[j]; --j; }
    ord[j + 1] = key;
  }
  const int wg = blockIdx.x;
  const int r0 = (wg < 256) ? (wg * 2) : ((wg - 256) * 2 + 1);
  const int b = ord[r0 >> 6];
  const int q0 = (r0 & 63) * 32;
  const int bq = b * SS + q0;
  const int len = lens_[b];

  // ---- dead q-tile: exact zeros ----
  if (q0 >= len) {
    float4 z = {0.f, 0.f, 0.f, 0.f};
    for (int row = 0; row < 32; ++row) {
      float4* sp = (float4*)(sc + (size_t)(bq + row) * SS);
      for (int c = tid; c < 512; c += 256) sp[c] = z;
    }
    float4* ap = (float4*)(att + (size_t)bq * DD);
    for (int c = tid; c < 2048; c += 256) ap[c] = z;
    return;
  }

  const int nt_act = (len + 63) >> 6;
  const char* cbf_b = (const char*)cbf + (size_t)b * SS * DD * 2;
  const char* cT_b  = (const char*)cT  + (size_t)b * SS * DD * 2;
  char* scr = (char*)sc + (size_t)bq * SS * 4 + 4096;   // p-scratch in sc rows

  auto stage_cs = [&](unsigned char* buf, int st) {
    const char* gb = cbf_b + ((size_t)st << 15);
    #pragma unroll
    for (int rr = 0; rr < 8; ++rr) {
      int chunk = rr * 256 + tid;
      int s = chunk >> 5, c = chunk & 31;
      gll16(gb + ((size_t)s << 9) + ((c ^ (s & 7)) << 4), buf + chunk * 16);
    }
  };
  auto stage_ct = [&](unsigned char* buf, int st) {
    const char* gb = cT_b + st * 128;
    #pragma unroll
    for (int rr = 0; rr < 8; ++rr) {
      int chunk = rr * 256 + tid;
      int d = chunk >> 3, c = chunk & 7;
      gll16(gb + (size_t)d * 4096 + ((c ^ (d & 7)) << 4), buf + chunk * 16);
    }
  };
  auto stage_p = [&](unsigned char* buf, int st) {
    const char* gb = scr + (size_t)st * 128;
    gll16(gb + (size_t)(tid >> 3) * 8192 + ((tid & 7) << 4), buf + tid * 16);
  };
  // scratch-store Ps buffer `which` (0/1) for tile st
  auto scr_store = [&](int which, int st) {
    const unsigned short* Psrc =
        (const unsigned short*)(smem + (which ? LPS1 : LPS0));
    int rr = tid >> 3, sb = tid & 7;
    bf16x8 v = *(const bf16x8*)(Psrc + rr * 72 + sb * 8);
    *(bf16x8*)(scr + (size_t)rr * 8192 + (size_t)st * 128 + ((sb ^ (rr & 7)) << 4)) = v;
  };

  // issue tile-0 staging before Q loads so gll16s fly under Q-load latency
  stage_cs(smem + LB0, 0);

  // ---- Q fragments ----
  bf16x8 qf[2][8];
  {
    const float* qb = qry + ((size_t)b * SS + q0) * DD;
    #pragma unroll
    for (int qi = 0; qi < 2; ++qi)
      #pragma unroll
      for (int kk = 0; kk < 8; ++kk) {
        const float4* qp = (const float4*)(qb + (size_t)(qi * 16 + l15) * DD + kk * 32 + l4 * 8);
        float4 x = qp[0], y = qp[1];
        bf16x8 f;
        f[0] = (short)f2bf(x.x); f[1] = (short)f2bf(x.y);
        f[2] = (short)f2bf(x.z); f[3] = (short)f2bf(x.w);
        f[4] = (short)f2bf(y.x); f[5] = (short)f2bf(y.y);
        f[6] = (short)f2bf(y.z); f[7] = (short)f2bf(y.w);
        qf[qi][kk] = f;
      }
  }

  // =============== phase 1: QK + exp; p -> Ps[t&1]; ONE barrier per iter ===============
  float ps0[4] = {0.f, 0.f, 0.f, 0.f};
  float ps1[4] = {0.f, 0.f, 0.f, 0.f};

  for (int t = 0; t < nt_act; ++t) {
    __syncthreads();                        // tile t staged+drained; Ps[t-1] writes visible
    unsigned char* cur = (t & 1) ? (smem + LB1) : (smem + LB0);
    if (t + 1 < nt_act) stage_cs((t & 1) ? (smem + LB0) : (smem + LB1), t + 1);
    if (t > 0) scr_store((t - 1) & 1, t - 1);   // store previous tile's p

    f32x4 a0 = {0.f, 0.f, 0.f, 0.f}, a1 = {0.f, 0.f, 0.f, 0.f};
    const unsigned char* rowp = cur + sl * 512;
    #pragma unroll
    for (int kk = 0; kk < 8; ++kk) {
      bf16x8 bfr = *(const bf16x8*)(rowp + (((kk * 4 + l4) ^ (sl & 7)) << 4));
      a0 = MFMA(qf[0][kk], bfr, a0, 0, 0, 0);
      a1 = MFMA(qf[1][kk], bfr, a1, 0, 0, 0);
    }
    bool sval = (t * 64 + sl) < len;
    unsigned short* Ps = (unsigned short*)(smem + ((t & 1) ? LPS1 : LPS0));
    #pragma unroll
    for (int qi = 0; qi < 2; ++qi) {
      #pragma unroll
      for (int j = 0; j < 4; ++j) {
        int row = qi * 16 + l4 * 4 + j;
        float e = sval ? __expf((qi ? a1[j] : a0[j]) * SCALE_INV) : 0.f;
        if (qi == 0) ps0[j] += e; else ps1[j] += e;
        Ps[row * 72 + sl] = f2bf(e);
      }
    }
  }
  __syncthreads();                          // last Ps visible
  scr_store((nt_act - 1) & 1, nt_act - 1);

  // ---- row-sum reduce -> invs ----
  #pragma unroll
  for (int off = 1; off < 16; off <<= 1)
    #pragma unroll
    for (int j = 0; j < 4; ++j) {
      ps0[j] += __shfl_xor(ps0[j], off, 64);
      ps1[j] += __shfl_xor(ps1[j], off, 64);
    }
  float* part = (float*)(smem + LPART);
  if (l15 == 0) {
    #pragma unroll
    for (int j = 0; j < 4; ++j) {
      part[wv * 32 + l4 * 4 + j] = ps0[j];
      part[wv * 32 + 16 + l4 * 4 + j] = ps1[j];
    }
  }
  __syncthreads();                          // partials visible; ALL scratch stores drained
  float* invs = (float*)(smem + LINV);
  if (tid < 32) {
    float rs = part[tid] + part[32 + tid] + part[64 + tid] + part[96 + tid];
    invs[tid] = (q0 + tid < len) ? (1.0f / fmaxf(rs, 1e-30f)) : 0.f;
  }

  // =============== phase 2: PV + normalized sc (no QK, no cs) ===============
  f32x4 av0[4] = {{0.f,0.f,0.f,0.f},{0.f,0.f,0.f,0.f},{0.f,0.f,0.f,0.f},{0.f,0.f,0.f,0.f}};
  f32x4 av1[4] = {{0.f,0.f,0.f,0.f},{0.f,0.f,0.f,0.f},{0.f,0.f,0.f,0.f},{0.f,0.f,0.f,0.f}};

  stage_p(smem + LPS0, 0);
  stage_ct(smem + LB0, 0);

  for (int t = 0; t < nt_act; ++t) {
    __syncthreads();                        // staged tile t + invs visible; t-1 reads done
    unsigned char* curP = (t & 1) ? (smem + LPS1) : (smem + LPS0);
    unsigned char* curC = (t & 1) ? (smem + LB1) : (smem + LB0);
    if (t + 1 < nt_act) {
      stage_p((t & 1) ? (smem + LPS0) : (smem + LPS1), t + 1);
      stage_ct((t & 1) ? (smem + LB0) : (smem + LB1), t + 1);
    }

    // PV fragments (2-way-max bank patterns)
    bf16x8 pa0[2], pa1[2], cb[4][2];
    #pragma unroll
    for (int k2 = 0; k2 < 2; ++k2) {
      pa0[k2] = *(const bf16x8*)(curP + l15 * 128 + (((k2 * 4 + l4) ^ (l15 & 7)) << 4));
      pa1[k2] = *(const bf16x8*)(curP + (16 + l15) * 128 + (((k2 * 4 + l4) ^ (l15 & 7)) << 4));
      #pragma unroll
      for (int nt = 0; nt < 4; ++nt) {
        int d = wv * 64 + nt * 16 + l15;
        cb[nt][k2] = *(const bf16x8*)(curC + d * 128 + (((k2 * 4 + l4) ^ (d & 7)) << 4));
      }
    }

    // normalized score write (vectorized, 32 B/thread)
    {
      int rr = tid >> 3, cbk = tid & 7;
      int sb = cbk ^ (rr & 7);
      bf16x8 pv = *(const bf16x8*)(curP + rr * 128 + cbk * 16);
      float inv0 = invs[rr];
      float4 f0, f1;
      f0.x = bf2f((unsigned short)pv[0]) * inv0; f0.y = bf2f((unsigned short)pv[1]) * inv0;
      f0.z = bf2f((unsigned short)pv[2]) * inv0; f0.w = bf2f((unsigned short)pv[3]) * inv0;
      f1.x = bf2f((unsigned short)pv[4]) * inv0; f1.y = bf2f((unsigned short)pv[5]) * inv0;
      f1.z = bf2f((unsigned short)pv[6]) * inv0; f1.w = bf2f((unsigned short)pv[7]) * inv0;
      float* sp = sc + (size_t)(bq + rr) * SS + t * 64 + sb * 8;
      *(float4*)sp = f0;
      *(float4*)(sp + 4) = f1;
    }

    #pragma unroll
    for (int k2 = 0; k2 < 2; ++k2)
      #pragma unroll
      for (int nt = 0; nt < 4; ++nt) {
        av0[nt] = MFMA(pa0[k2], cb[nt][k2], av0[nt], 0, 0, 0);
        av1[nt] = MFMA(pa1[k2], cb[nt][k2], av1[nt], 0, 0, 0);
      }
  }

  // zero-fill score columns [nt_act*64, SS) (erases leftover scratch bytes)
  {
    int s_start = nt_act * 64;
    int rem4 = (SS - s_start) >> 2;
    if (rem4 > 0) {
      __syncthreads();                      // all p reads done before overwriting scratch
      float4 z = {0.f, 0.f, 0.f, 0.f};
      for (int row = 0; row < 32; ++row)
        for (int c = tid; c < rem4; c += 256)
          *(float4*)(sc + (size_t)(bq + row) * SS + s_start + c * 4) = z;
    }
  }

  // write attended = av * invs
  #pragma unroll
  for (int nt = 0; nt < 4; ++nt)
    #pragma unroll
    for (int j = 0; j < 4; ++j) {
      int col = wv * 64 + nt * 16 + l15;
      int row0 = l4 * 4 + j;
      att[(size_t)(bq + row0) * DD + col] = av0[nt][j] * invs[row0];
      att[(size_t)(bq + 16 + row0) * DD + col] = av1[nt][j] * invs[16 + row0];
    }
}

extern "C" void kernel_launch(void* const* d_in, const int* in_sizes, int n_in,
                              void* d_out, int out_size, void* d_ws, size_t ws_size,
                              hipStream_t stream) {
  const float* ctx = (const float*)d_in[0];
  const float* qry = (const float*)d_in[1];
  const int* len = (const int*)d_in[2];
  float* att = (float*)d_out;
  float* sc = att + (size_t)NB * SS * DD;

  const size_t nqd = (size_t)NB * SS * DD;
  const size_t need = nqd * 4;   // cbf + cT (bf16 each) = 16.8 MB

  if (ws_size >= need) {
    unsigned short* cbf = (unsigned short*)d_ws;
    unsigned short* cTp = cbf + nqd;
    preconv<<<dim3(SS / 64, DD / 64, NB), dim3(256), 0, stream>>>(ctx, len, cbf, cTp);
    attn_v16<<<dim3(512), dim3(256), 0, stream>>>(cbf, cTp, qry, len, att, sc);
  }
}

// Round 17
// 68.604 us; speedup vs baseline: 1.1949x; 1.1949x over previous
//
#include <hip/hip_runtime.h>
#include <hip/hip_bf16.h>

#define NB 8
#define SS 2048
#define DD 256
#define SCALE_INV 0.0625f

typedef __attribute__((ext_vector_type(8))) short bf16x8;
typedef __attribute__((ext_vector_type(4))) float f32x4;

#define MFMA __builtin_amdgcn_mfma_f32_16x16x32_bf16

// LDS: cs dbuf 64K, Ps dbuf 2x4608, part 512, invs 128  -> 75392 B (2 blocks/CU)
#define LB0   0
#define LB1   32768
#define LPS0  65536
#define LPS1  70144
#define LPART 74752
#define LINV  75264
#define LSMEM 75392

static __device__ __forceinline__ unsigned short f2bf(float f) {
  unsigned int u = __builtin_bit_cast(unsigned int, f);
  u += 0x7FFFu + ((u >> 16) & 1u);
  return (unsigned short)(u >> 16);
}
static __device__ __forceinline__ float bf2f(unsigned short s) {
  unsigned int u = ((unsigned int)s) << 16;
  return __builtin_bit_cast(float, u);
}

static __device__ __forceinline__ void gll16(const void* g, void* l) {
  __builtin_amdgcn_global_load_lds(
      (const __attribute__((address_space(1))) unsigned int*)g,
      (__attribute__((address_space(3))) unsigned int*)l, 16, 0, 0);
}

static __device__ __forceinline__ int load_len(const int* lp, int b) {
  bool is64 = ((lp[1] | lp[3] | lp[5] | lp[7]) == 0);
  return is64 ? lp[2 * b] : lp[b];
}

// ---------------- ctx f32 -> bf16 + transposed bf16 (proven) + dead-row skip ----------------
__global__ __launch_bounds__(256)
void preconv(const float* __restrict__ ctx,
             const int* __restrict__ lenp,
             unsigned short* __restrict__ cbf,   // [b][s][d]
             unsigned short* __restrict__ cT)    // [b][d][s]
{
  __shared__ unsigned short T[64][68];
  const int tid = threadIdx.x;
  const int s0 = blockIdx.x * 64, d0 = blockIdx.y * 64, b = blockIdx.z;

  // rows >= len[b] are never consumed by attn (sval-masked) -> skip conversion
  if (s0 >= load_len(lenp, b)) return;

  const int r = tid >> 4, c4 = tid & 15;

  #pragma unroll
  for (int i = 0; i < 4; ++i) {
    int row = i * 16 + r;
    size_t gi = ((size_t)(b * SS + s0 + row)) * DD + d0 + c4 * 4;
    float4 v = *(const float4*)(ctx + gi);
    ushort4 o;
    o.x = f2bf(v.x); o.y = f2bf(v.y); o.z = f2bf(v.z); o.w = f2bf(v.w);
    *(ushort4*)(cbf + gi) = o;
    T[c4 * 4 + 0][row] = o.x;
    T[c4 * 4 + 1][row] = o.y;
    T[c4 * 4 + 2][row] = o.z;
    T[c4 * 4 + 3][row] = o.w;
  }
  __syncthreads();
  const int rr = tid >> 2, cc = tid & 3;
  #pragma unroll
  for (int j = 0; j < 4; ++j) {
    size_t go = ((size_t)(b * DD + d0 + rr)) * SS + s0 + cc * 16 + j * 4;
    *(ushort4*)(cT + go) = *(const ushort4*)&T[rr][cc * 16 + j * 4];
  }
}

// ---------------- fused attention v17 = v13 (proven 69.5us) ----------------
__global__ __launch_bounds__(256, 2)
void attn_v17(const unsigned short* __restrict__ cbf,
              const unsigned short* __restrict__ cT,
              const float* __restrict__ qry,
              const int* __restrict__ lenp,
              float* __restrict__ att,
              float* __restrict__ sc)
{
  __shared__ __align__(16) unsigned char smem[LSMEM];

  const int tid = threadIdx.x;
  const int wv = tid >> 6;
  const int lane = tid & 63;
  const int l15 = lane & 15;
  const int l4 = lane >> 4;
  const int sl = wv * 16 + l15;

  // ---- length-aware ANTI-pairing mapping (R9/R13 proven; R16 falsified adjacent) ----
  int lens_[8];
  #pragma unroll
  for (int i = 0; i < 8; ++i) lens_[i] = load_len(lenp, i);
  int ord[8] = {0, 1, 2, 3, 4, 5, 6, 7};
  for (int i = 1; i < 8; ++i) {
    int key = ord[i], kl = lens_[key], j = i - 1;
    while (j >= 0 && lens_[ord[j]] < kl) { ord[j + 1] = ord[j]; --j; }
    ord[j + 1] = key;
  }
  const int wg = blockIdx.x;
  const int r0 = (wg < 256) ? wg : 767 - wg;
  const int b = ord[r0 >> 6];
  const int q0 = (r0 & 63) * 32;
  const int bq = b * SS + q0;
  const int len = lens_[b];

  // ---- dead q-tile: exact zeros ----
  if (q0 >= len) {
    float4 z = {0.f, 0.f, 0.f, 0.f};
    for (int row = 0; row < 32; ++row) {
      float4* sp = (float4*)(sc + (size_t)(bq + row) * SS);
      for (int c = tid; c < 512; c += 256) sp[c] = z;
    }
    float4* ap = (float4*)(att + (size_t)bq * DD);
    for (int c = tid; c < 2048; c += 256) ap[c] = z;
    return;
  }

  const int nt_act = (len + 63) >> 6;
  const char* cbf_b = (const char*)cbf + (size_t)b * SS * DD * 2;
  const char* cT_b  = (const char*)cT  + (size_t)b * SS * DD * 2;
  char* scr = (char*)sc + (size_t)bq * SS * 4 + 4096;   // p-scratch in sc rows

  auto stage_cs = [&](unsigned char* buf, int st) {
    const char* gb = cbf_b + ((size_t)st << 15);
    #pragma unroll
    for (int rr = 0; rr < 8; ++rr) {
      int chunk = rr * 256 + tid;
      int s = chunk >> 5, c = chunk & 31;
      gll16(gb + ((size_t)s << 9) + ((c ^ (s & 7)) << 4), buf + chunk * 16);
    }
  };
  auto stage_ct = [&](unsigned char* buf, int st) {
    const char* gb = cT_b + st * 128;
    #pragma unroll
    for (int rr = 0; rr < 8; ++rr) {
      int chunk = rr * 256 + tid;
      int d = chunk >> 3, c = chunk & 7;
      gll16(gb + (size_t)d * 4096 + ((c ^ (d & 7)) << 4), buf + chunk * 16);
    }
  };
  auto stage_p = [&](unsigned char* buf, int st) {
    const char* gb = scr + (size_t)st * 128;
    gll16(gb + (size_t)(tid >> 3) * 8192 + ((tid & 7) << 4), buf + tid * 16);
  };
  // scratch-store Ps buffer `which` (0/1) for tile st
  auto scr_store = [&](int which, int st) {
    const unsigned short* Psrc =
        (const unsigned short*)(smem + (which ? LPS1 : LPS0));
    int rr = tid >> 3, sb = tid & 7;
    bf16x8 v = *(const bf16x8*)(Psrc + rr * 72 + sb * 8);
    *(bf16x8*)(scr + (size_t)rr * 8192 + (size_t)st * 128 + ((sb ^ (rr & 7)) << 4)) = v;
  };

  // issue tile-0 staging before Q loads so gll16s fly under Q-load latency
  stage_cs(smem + LB0, 0);

  // ---- Q fragments ----
  bf16x8 qf[2][8];
  {
    const float* qb = qry + ((size_t)b * SS + q0) * DD;
    #pragma unroll
    for (int qi = 0; qi < 2; ++qi)
      #pragma unroll
      for (int kk = 0; kk < 8; ++kk) {
        const float4* qp = (const float4*)(qb + (size_t)(qi * 16 + l15) * DD + kk * 32 + l4 * 8);
        float4 x = qp[0], y = qp[1];
        bf16x8 f;
        f[0] = (short)f2bf(x.x); f[1] = (short)f2bf(x.y);
        f[2] = (short)f2bf(x.z); f[3] = (short)f2bf(x.w);
        f[4] = (short)f2bf(y.x); f[5] = (short)f2bf(y.y);
        f[6] = (short)f2bf(y.z); f[7] = (short)f2bf(y.w);
        qf[qi][kk] = f;
      }
  }

  // =============== phase 1: QK + exp; p -> Ps[t&1]; ONE barrier per iter ===============
  float ps0[4] = {0.f, 0.f, 0.f, 0.f};
  float ps1[4] = {0.f, 0.f, 0.f, 0.f};

  for (int t = 0; t < nt_act; ++t) {
    __syncthreads();                        // tile t staged+drained; Ps[t-1] writes visible
    unsigned char* cur = (t & 1) ? (smem + LB1) : (smem + LB0);
    if (t + 1 < nt_act) stage_cs((t & 1) ? (smem + LB0) : (smem + LB1), t + 1);
    if (t > 0) scr_store((t - 1) & 1, t - 1);   // store previous tile's p

    f32x4 a0 = {0.f, 0.f, 0.f, 0.f}, a1 = {0.f, 0.f, 0.f, 0.f};
    const unsigned char* rowp = cur + sl * 512;
    #pragma unroll
    for (int kk = 0; kk < 8; ++kk) {
      bf16x8 bfr = *(const bf16x8*)(rowp + (((kk * 4 + l4) ^ (sl & 7)) << 4));
      a0 = MFMA(qf[0][kk], bfr, a0, 0, 0, 0);
      a1 = MFMA(qf[1][kk], bfr, a1, 0, 0, 0);
    }
    bool sval = (t * 64 + sl) < len;
    unsigned short* Ps = (unsigned short*)(smem + ((t & 1) ? LPS1 : LPS0));
    #pragma unroll
    for (int qi = 0; qi < 2; ++qi) {
      #pragma unroll
      for (int j = 0; j < 4; ++j) {
        int row = qi * 16 + l4 * 4 + j;
        float e = sval ? __expf((qi ? a1[j] : a0[j]) * SCALE_INV) : 0.f;
        if (qi == 0) ps0[j] += e; else ps1[j] += e;
        Ps[row * 72 + sl] = f2bf(e);
      }
    }
  }
  __syncthreads();                          // last Ps visible
  scr_store((nt_act - 1) & 1, nt_act - 1);

  // ---- row-sum reduce -> invs ----
  #pragma unroll
  for (int off = 1; off < 16; off <<= 1)
    #pragma unroll
    for (int j = 0; j < 4; ++j) {
      ps0[j] += __shfl_xor(ps0[j], off, 64);
      ps1[j] += __shfl_xor(ps1[j], off, 64);
    }
  float* part = (float*)(smem + LPART);
  if (l15 == 0) {
    #pragma unroll
    for (int j = 0; j < 4; ++j) {
      part[wv * 32 + l4 * 4 + j] = ps0[j];
      part[wv * 32 + 16 + l4 * 4 + j] = ps1[j];
    }
  }
  __syncthreads();                          // partials visible; ALL scratch stores drained
  float* invs = (float*)(smem + LINV);
  if (tid < 32) {
    float rs = part[tid] + part[32 + tid] + part[64 + tid] + part[96 + tid];
    invs[tid] = (q0 + tid < len) ? (1.0f / fmaxf(rs, 1e-30f)) : 0.f;
  }

  // =============== phase 2: PV + normalized sc (no QK, no cs) ===============
  f32x4 av0[4] = {{0.f,0.f,0.f,0.f},{0.f,0.f,0.f,0.f},{0.f,0.f,0.f,0.f},{0.f,0.f,0.f,0.f}};
  f32x4 av1[4] = {{0.f,0.f,0.f,0.f},{0.f,0.f,0.f,0.f},{0.f,0.f,0.f,0.f},{0.f,0.f,0.f,0.f}};

  stage_p(smem + LPS0, 0);
  stage_ct(smem + LB0, 0);

  for (int t = 0; t < nt_act; ++t) {
    __syncthreads();                        // staged tile t + invs visible; t-1 reads done
    unsigned char* curP = (t & 1) ? (smem + LPS1) : (smem + LPS0);
    unsigned char* curC = (t & 1) ? (smem + LB1) : (smem + LB0);
    if (t + 1 < nt_act) {
      stage_p((t & 1) ? (smem + LPS0) : (smem + LPS1), t + 1);
      stage_ct((t & 1) ? (smem + LB0) : (smem + LB1), t + 1);
    }

    // PV fragments (2-way-max bank patterns)
    bf16x8 pa0[2], pa1[2], cb[4][2];
    #pragma unroll
    for (int k2 = 0; k2 < 2; ++k2) {
      pa0[k2] = *(const bf16x8*)(curP + l15 * 128 + (((k2 * 4 + l4) ^ (l15 & 7)) << 4));
      pa1[k2] = *(const bf16x8*)(curP + (16 + l15) * 128 + (((k2 * 4 + l4) ^ (l15 & 7)) << 4));
      #pragma unroll
      for (int nt = 0; nt < 4; ++nt) {
        int d = wv * 64 + nt * 16 + l15;
        cb[nt][k2] = *(const bf16x8*)(curC + d * 128 + (((k2 * 4 + l4) ^ (d & 7)) << 4));
      }
    }

    // normalized score write (vectorized, 32 B/thread)
    {
      int rr = tid >> 3, cbk = tid & 7;
      int sb = cbk ^ (rr & 7);
      bf16x8 pv = *(const bf16x8*)(curP + rr * 128 + cbk * 16);
      float inv0 = invs[rr];
      float4 f0, f1;
      f0.x = bf2f((unsigned short)pv[0]) * inv0; f0.y = bf2f((unsigned short)pv[1]) * inv0;
      f0.z = bf2f((unsigned short)pv[2]) * inv0; f0.w = bf2f((unsigned short)pv[3]) * inv0;
      f1.x = bf2f((unsigned short)pv[4]) * inv0; f1.y = bf2f((unsigned short)pv[5]) * inv0;
      f1.z = bf2f((unsigned short)pv[6]) * inv0; f1.w = bf2f((unsigned short)pv[7]) * inv0;
      float* sp = sc + (size_t)(bq + rr) * SS + t * 64 + sb * 8;
      *(float4*)sp = f0;
      *(float4*)(sp + 4) = f1;
    }

    #pragma unroll
    for (int k2 = 0; k2 < 2; ++k2)
      #pragma unroll
      for (int nt = 0; nt < 4; ++nt) {
        av0[nt] = MFMA(pa0[k2], cb[nt][k2], av0[nt], 0, 0, 0);
        av1[nt] = MFMA(pa1[k2], cb[nt][k2], av1[nt], 0, 0, 0);
      }
  }

  // zero-fill score columns [nt_act*64, SS) (erases leftover scratch bytes)
  {
    int s_start = nt_act * 64;
    int rem4 = (SS - s_start) >> 2;
    if (rem4 > 0) {
      __syncthreads();                      // all p reads done before overwriting scratch
      float4 z = {0.f, 0.f, 0.f, 0.f};
      for (int row = 0; row < 32; ++row)
        for (int c = tid; c < rem4; c += 256)
          *(float4*)(sc + (size_t)(bq + row) * SS + s_start + c * 4) = z;
    }
  }

  // write attended = av * invs
  #pragma unroll
  for (int nt = 0; nt < 4; ++nt)
    #pragma unroll
    for (int j = 0; j < 4; ++j) {
      int col = wv * 64 + nt * 16 + l15;
      int row0 = l4 * 4 + j;
      att[(size_t)(bq + row0) * DD + col] = av0[nt][j] * invs[row0];
      att[(size_t)(bq + 16 + row0) * DD + col] = av1[nt][j] * invs[16 + row0];
    }
}

extern "C" void kernel_launch(void* const* d_in, const int* in_sizes, int n_in,
                              void* d_out, int out_size, void* d_ws, size_t ws_size,
                              hipStream_t stream) {
  const float* ctx = (const float*)d_in[0];
  const float* qry = (const float*)d_in[1];
  const int* len = (const int*)d_in[2];
  float* att = (float*)d_out;
  float* sc = att + (size_t)NB * SS * DD;

  const size_t nqd = (size_t)NB * SS * DD;
  const size_t need = nqd * 4;   // cbf + cT (bf16 each) = 16.8 MB

  if (ws_size >= need) {
    unsigned short* cbf = (unsigned short*)d_ws;
    unsigned short* cTp = cbf + nqd;
    preconv<<<dim3(SS / 64, DD / 64, NB), dim3(256), 0, stream>>>(ctx, len, cbf, cTp);
    attn_v17<<<dim3(512), dim3(256), 0, stream>>>(cbf, cTp, qry, len, att, sc);
  }
}